// Round 1
// baseline (529.765 us; speedup 1.0000x reference)
//
#include <hip/hip_runtime.h>
#include <stdint.h>

#define SEQ    2048
#define HIDDEN 4096
#define NQH    32
#define NKVH   2
#define HD     128
#define QKVN   4608   // (32+4)*128
#define ATTN_N 4096   // 32*128

typedef short bf16x8 __attribute__((ext_vector_type(8)));
typedef float f32x4  __attribute__((ext_vector_type(4)));

#define ASYNC16(gp, lp) __builtin_amdgcn_global_load_lds( \
    (const __attribute__((address_space(1))) void*)(gp),  \
    (__attribute__((address_space(3))) void*)(lp), 16, 0, 0)

#define MFMA16(a, b, c) __builtin_amdgcn_mfma_f32_16x16x32_bf16((a), (b), (c), 0, 0, 0)

__device__ __forceinline__ float bf2f(unsigned short u) {
  union { unsigned int i; float f; } v; v.i = ((unsigned int)u) << 16; return v.f;
}
__device__ __forceinline__ unsigned short f2bf(float f) {
  union { float f; unsigned int i; } v; v.f = f;
  unsigned int r = v.i + 0x7fffu + ((v.i >> 16) & 1u);  // RNE
  return (unsigned short)(r >> 16);
}

// ---- dtype probe: bf16 arrays have sane exponents at every index; fp32 read
// ---- as ushort has uniform-random exponent bits at even indices. flag=1 -> fp32
__global__ void detect_dtype(const unsigned short* __restrict__ hs, int* __restrict__ flag) {
  int bad = 0;
  for (int i = 0; i < 128; i += 2) {
    const int e = (hs[i] >> 7) & 0xFF;
    if (e < 100 || e > 140) bad++;
  }
  *flag = (bad > 16) ? 1 : 0;
}

__global__ void to_bf16_any(const void* __restrict__ in, unsigned short* __restrict__ out,
                            int n4, const int* __restrict__ flag) {
  const int i = blockIdx.x * blockDim.x + threadIdx.x;
  if (i >= n4) return;
  if (*flag) {
    const float4 f = ((const float4*)in)[i];
    ushort4 u; u.x = f2bf(f.x); u.y = f2bf(f.y); u.z = f2bf(f.z); u.w = f2bf(f.w);
    ((ushort4*)out)[i] = u;
  } else {
    ((ushort4*)out)[i] = ((const ushort4*)in)[i];
  }
}

__global__ void to_f32_any(const void* __restrict__ in, float* __restrict__ out,
                           int n4, const int* __restrict__ flag) {
  const int i = blockIdx.x * blockDim.x + threadIdx.x;
  if (i >= n4) return;
  if (*flag) {
    ((float4*)out)[i] = ((const float4*)in)[i];
  } else {
    const ushort4 u = ((const ushort4*)in)[i];
    float4 f; f.x = bf2f(u.x); f.y = bf2f(u.y); f.z = bf2f(u.z); f.w = bf2f(u.w);
    ((float4*)out)[i] = f;
  }
}

// ---- transpose + convert: out[c][r] (bf16) = in[r][c]; in is R x C ----
__global__ void transpose_any(const void* __restrict__ in, unsigned short* __restrict__ out,
                              int R, int C, const int* __restrict__ flag) {
  __shared__ unsigned short t[32][36];
  const int r0 = blockIdx.y * 32, c0 = blockIdx.x * 32;
  const int lr = threadIdx.x >> 3;
  const int lc = (threadIdx.x & 7) << 2;
  unsigned short v0, v1, v2, v3;
  if (*flag) {
    const float4 f = *(const float4*)((const float*)in + (size_t)(r0 + lr) * C + c0 + lc);
    v0 = f2bf(f.x); v1 = f2bf(f.y); v2 = f2bf(f.z); v3 = f2bf(f.w);
  } else {
    const ushort4 u = *(const ushort4*)((const unsigned short*)in + (size_t)(r0 + lr) * C + c0 + lc);
    v0 = u.x; v1 = u.y; v2 = u.z; v3 = u.w;
  }
  t[lr][lc] = v0; t[lr][lc + 1] = v1; t[lr][lc + 2] = v2; t[lr][lc + 3] = v3;
  __syncthreads();
  unsigned short* op = out + (size_t)(c0 + lr) * R + r0 + lc;
  ushort4 w;
  w.x = t[lc][lr]; w.y = t[lc + 1][lr]; w.z = t[lc + 2][lr]; w.w = t[lc + 3][lr];
  *(ushort4*)op = w;
}

// ======================= 256x256 8-phase GEMM (T2+T3+T4+T5) ==================
// C = A(MxK) * Bt(NxK)^T (+bias), bf16 in, fp32 acc.
// 512 thr = 8 waves (2M x 4N), per-wave 128x64 out -> acc[8][4] f32x4.
// BK=64; LDS chunk = operand x k-half (256 rows x 32k = 16KB), 2 gload rounds.
// 4 phases per K-tile:
//   ph0: read A-k0 frags(8) + B-k0 j0..1 | stage A-k0(t+1) | bar | 16 MFMA | bar
//   ph1: read B-k0 j2..3                 | stage B-k0(t+1) | bar | 16 MFMA | vmcnt(4) bar
//   ph2: read A-k1 frags(8) + B-k1 j0..1 | stage A-k1(t+1) | bar | 16 MFMA | bar
//   ph3: read B-k1 j2..3                 | stage B-k1(t+1) | bar | 16 MFMA | vmcnt(4) bar
// Counted vmcnt(4): at the ph1-end wait, A-k1/B-k1(t) (issued 2 phases before
// the previous tile's waits; everything newer = 4 loads) are complete; at the
// ph3-end wait, A-k0/B-k0(t+1) are complete. Writes into buf b^1 never touch
// regions read this tile, and all reads of a region precede (by >=1 barrier)
// the issue of the next write to it. Raw s_barrier (NOT __syncthreads) so the
// compiler never drains vmcnt to 0 in the loop.
// LDS bank swizzle: 16B slot s of row r holds global k-chunk s^((r>>1)&3)
// (source-side pre-swizzle; proven conflict-free on this HW: BANK_CONFLICT=0).
__global__ __launch_bounds__(512, 2)
void gemm_bt_8ph(const unsigned short* __restrict__ A,
                 const unsigned short* __restrict__ Bt,
                 const float* __restrict__ bias,
                 void* __restrict__ C,
                 int M, int N, int K, const int* __restrict__ of32) {
  // [buf 2][chunk 4][8192 elems]; chunk: 0=A k0..31, 1=B k0..31, 2=A k32..63, 3=B k32..63
  __shared__ __attribute__((aligned(16))) unsigned short lds[65536];  // 128 KiB
  const int tid  = threadIdx.x;
  const int wave = tid >> 6, lane = tid & 63;
  const int quad = lane >> 4, l16 = lane & 15;
  const int m0 = blockIdx.y * 256, n0 = blockIdx.x * 256;
  const int wm = (wave >> 2) * 128, wn = (wave & 3) * 64;

  // staging map: thread covers rows srow (round 0) and srow+128 (round 1);
  // slot (tid&3) holds global k-chunk (tid&3)^((srow>>1)&3) (invariant to +128)
  const int srow = tid >> 2;
  const int g8   = (((tid & 3) ^ ((srow >> 1) & 3)) << 3);
  const unsigned short* gA = A  + (size_t)(m0 + srow) * K + g8;
  const unsigned short* gB = Bt + (size_t)(n0 + srow) * K + g8;
  const size_t rstep = (size_t)128 * K;

  // frag-read: row = base16 + l16 -> ((row>>1)&3) == ((l16>>1)&3)
  const int rsw   = ((quad ^ ((l16 >> 1) & 3)) << 3);
  const int aBase = (wm + l16) * 32 + rsw;
  const int bBase = (wn + l16) * 32 + rsw;

  f32x4 acc[8][4] = {};
  const int nt = K >> 6;

#define STAGE(bufb, p, kbase) do {                                        \
    const unsigned short* _s = ((p) & 1) ? gB : gA;                       \
    const int _ko = (kbase) + (((p) >> 1) << 5);                          \
    unsigned short* _d = &lds[((((bufb) << 2) | (p)) << 13) + tid * 8];   \
    ASYNC16(_s + _ko, _d);                                                \
    ASYNC16(_s + rstep + _ko, _d + 4096);                                 \
  } while (0)

#define BARX() do { asm volatile("" ::: "memory");          \
    __builtin_amdgcn_s_barrier();                           \
    asm volatile("" ::: "memory"); } while (0)

  // prologue: all 4 chunks of tile 0; complete A-k0,B-k0 before ph0 reads
  STAGE(0, 0, 0);
  STAGE(0, 1, 0);
  STAGE(0, 2, 0);
  STAGE(0, 3, 0);
  asm volatile("s_waitcnt vmcnt(4)" ::: "memory");
  BARX();

  for (int t = 0; t < nt; ++t) {
    const int b   = t & 1;
    const int kb1 = (t + 1) << 6;
    const bool pf = (t + 1 < nt);
    const int c0 = ((b << 2) | 0) << 13;
    const int c1 = ((b << 2) | 1) << 13;
    const int c2 = ((b << 2) | 2) << 13;
    const int c3 = ((b << 2) | 3) << 13;
    bf16x8 af[8], bf0, bf1;

    // ---------------- phase 0: k0, acc[:][0..1] ----------------
#pragma unroll
    for (int i = 0; i < 8; i++) af[i] = *(const bf16x8*)&lds[c0 + aBase + i * 512];
    bf0 = *(const bf16x8*)&lds[c1 + bBase + 0 * 512];
    bf1 = *(const bf16x8*)&lds[c1 + bBase + 1 * 512];
    if (pf) STAGE(b ^ 1, 0, kb1);
    BARX();
    __builtin_amdgcn_s_setprio(1);
#pragma unroll
    for (int i = 0; i < 8; i++) acc[i][0] = MFMA16(af[i], bf0, acc[i][0]);
#pragma unroll
    for (int i = 0; i < 8; i++) acc[i][1] = MFMA16(af[i], bf1, acc[i][1]);
    __builtin_amdgcn_s_setprio(0);
    BARX();

    // ---------------- phase 1: k0, acc[:][2..3] ----------------
    bf0 = *(const bf16x8*)&lds[c1 + bBase + 2 * 512];
    bf1 = *(const bf16x8*)&lds[c1 + bBase + 3 * 512];
    if (pf) STAGE(b ^ 1, 1, kb1);
    BARX();
    __builtin_amdgcn_s_setprio(1);
#pragma unroll
    for (int i = 0; i < 8; i++) acc[i][2] = MFMA16(af[i], bf0, acc[i][2]);
#pragma unroll
    for (int i = 0; i < 8; i++) acc[i][3] = MFMA16(af[i], bf1, acc[i][3]);
    __builtin_amdgcn_s_setprio(0);
    if (t == nt - 1) asm volatile("s_waitcnt vmcnt(0)" ::: "memory");
    else             asm volatile("s_waitcnt vmcnt(4)" ::: "memory");
    BARX();

    // ---------------- phase 2: k1, acc[:][0..1] ----------------
#pragma unroll
    for (int i = 0; i < 8; i++) af[i] = *(const bf16x8*)&lds[c2 + aBase + i * 512];
    bf0 = *(const bf16x8*)&lds[c3 + bBase + 0 * 512];
    bf1 = *(const bf16x8*)&lds[c3 + bBase + 1 * 512];
    if (pf) STAGE(b ^ 1, 2, kb1);
    BARX();
    __builtin_amdgcn_s_setprio(1);
#pragma unroll
    for (int i = 0; i < 8; i++) acc[i][0] = MFMA16(af[i], bf0, acc[i][0]);
#pragma unroll
    for (int i = 0; i < 8; i++) acc[i][1] = MFMA16(af[i], bf1, acc[i][1]);
    __builtin_amdgcn_s_setprio(0);
    BARX();

    // ---------------- phase 3: k1, acc[:][2..3] ----------------
    bf0 = *(const bf16x8*)&lds[c3 + bBase + 2 * 512];
    bf1 = *(const bf16x8*)&lds[c3 + bBase + 3 * 512];
    if (pf) STAGE(b ^ 1, 3, kb1);
    BARX();
    __builtin_amdgcn_s_setprio(1);
#pragma unroll
    for (int i = 0; i < 8; i++) acc[i][2] = MFMA16(af[i], bf0, acc[i][2]);
#pragma unroll
    for (int i = 0; i < 8; i++) acc[i][3] = MFMA16(af[i], bf1, acc[i][3]);
    __builtin_amdgcn_s_setprio(0);
    asm volatile("s_waitcnt vmcnt(4)" ::: "memory");
    BARX();
  }
#undef STAGE
#undef BARX

  const int wf32 = of32 ? *of32 : 0;
#pragma unroll
  for (int j = 0; j < 4; j++) {
    const int col = n0 + wn + j * 16 + l16;
    const float bv = bias ? bias[col] : 0.0f;
#pragma unroll
    for (int i = 0; i < 8; i++) {
#pragma unroll
      for (int r = 0; r < 4; r++) {
        const int row = m0 + wm + i * 16 + quad * 4 + r;  // C/D: row=quad*4+reg, col=l16
        const float v = acc[i][j][r] + bv;
        const size_t off = (size_t)row * N + col;
        if (wf32) ((float*)C)[off] = v;
        else      ((unsigned short*)C)[off] = f2bf(v);
      }
    }
  }
}

// --------- RoPE (interleaved) + split into Q (scaled), K, V^T buffers ---------
__global__ void rope_split(const unsigned short* __restrict__ qkv,
                           const float* __restrict__ cosb,
                           const float* __restrict__ sinb,
                           unsigned short* __restrict__ qb,
                           unsigned short* __restrict__ kb,
                           unsigned short* __restrict__ vtb) {
  const int s = blockIdx.x;
  const unsigned short* row = qkv + (size_t)s * QKVN;
  const float sc = 0.08838834764831845f * 1.44269504088896341f;  // 1/sqrt(128)*log2(e)
  for (int p = threadIdx.x; p < QKVN / 2; p += blockDim.x) {
    const int col = p << 1;
    const int head = col >> 7;
    const int d = col & 127;
    float x0 = bf2f(row[col]), x1 = bf2f(row[col + 1]);
    float y0 = x0, y1 = x1;
    if (d < 64) {
      const float c  = cosb[s * 64 + (d >> 1)];
      const float sn = sinb[s * 64 + (d >> 1)];
      y0 = x0 * c - x1 * sn;
      y1 = x1 * c + x0 * sn;
    }
    if (head < NQH) {
      const size_t o = (size_t)head * SEQ * HD + (size_t)s * HD + d;
      qb[o] = f2bf(y0 * sc); qb[o + 1] = f2bf(y1 * sc);
    } else if (head < NQH + NKVH) {
      const size_t o = (size_t)(head - NQH) * SEQ * HD + (size_t)s * HD + d;
      kb[o] = f2bf(y0); kb[o + 1] = f2bf(y1);
    } else {
      const size_t o = (size_t)(head - NQH - NKVH) * HD * SEQ + (size_t)d * SEQ + s;
      vtb[o] = f2bf(x0); vtb[o + SEQ] = f2bf(x1);  // V: no rope, transposed
    }
  }
}

// ------------------- causal flash attention, bf16 MFMA ------------------------
// grid (32 heads, 32 q-tiles of 64 rows), heavy-first. 4 waves/block, 16 rows/wave.
// K/V staged in LDS via global_load_lds with XOR chunk swizzle. Row-sums of P
// computed by an extra MFMA against an all-ones B-frag (replaces shuffle tree).
__global__ __launch_bounds__(256, 3)
void attn_fwd(const unsigned short* __restrict__ qb,
              const unsigned short* __restrict__ kb,
              const unsigned short* __restrict__ vtb,
              unsigned short* __restrict__ ob) {
  const int h = blockIdx.x;
  const int qt = 31 - (int)blockIdx.y;            // heavy-first scheduling
  const int tid = threadIdx.x;
  const int wave = tid >> 6, lane = tid & 63;
  const int quad = lane >> 4, l16 = lane & 15;
  const int q0 = qt * 64 + wave * 16;
  const unsigned short* qh  = qb  + (size_t)h * SEQ * HD;
  const unsigned short* kh  = kb  + (size_t)(h >> 4) * SEQ * HD;
  const unsigned short* vth = vtb + (size_t)(h >> 4) * HD * SEQ;

  __shared__ __attribute__((aligned(16))) unsigned short Ks[64 * 128];   // [key][d], chunk-swizzled
  __shared__ __attribute__((aligned(16))) unsigned short Vs[128 * 64];   // [d][key], chunk-swizzled
  __shared__ __attribute__((aligned(16))) unsigned short plds[4][16][80];

  bf16x8 qf[4];
#pragma unroll
  for (int kbk = 0; kbk < 4; kbk++)   // A-frag: A[m=l16][k=quad*8+j]
    qf[kbk] = *(const bf16x8*)&qh[(size_t)(q0 + l16) * HD + kbk * 32 + quad * 8];

  bf16x8 onesf;
#pragma unroll
  for (int i = 0; i < 8; i++) onesf[i] = (short)0x3F80;   // bf16 1.0

  f32x4 oacc[8] = {};
  f32x4 lacc = {};
  float mrow[4] = {-1e30f, -1e30f, -1e30f, -1e30f};

  for (int kt = 0; kt <= qt; kt++) {
    const int kbase = kt * 64;
    __syncthreads();                   // all waves done reading prev K/V tiles
    // K tile: chunk j of 1024: key=j>>4, LDS slot j&15 holds global chunk (j&15)^(key&15)
#pragma unroll
    for (int c = 0; c < 4; c++) {
      const int j = c * 256 + tid;
      const int key = j >> 4;
      const int g = (j & 15) ^ (key & 15);
      ASYNC16(kh + (size_t)(kbase + key) * HD + g * 8, (unsigned short*)Ks + j * 8);
    }
    // V tile: chunk j of 1024: d=j>>3, slot j&7 holds chunk (j&7)^(d&7)
#pragma unroll
    for (int c = 0; c < 4; c++) {
      const int j = c * 256 + tid;
      const int d = j >> 3;
      const int g = (j & 7) ^ (d & 7);
      ASYNC16(vth + (size_t)d * SEQ + kbase + g * 8, (unsigned short*)Vs + j * 8);
    }
    __syncthreads();                   // vmcnt drained: tiles visible

    f32x4 sv[4] = {};
#pragma unroll
    for (int kbk = 0; kbk < 4; kbk++) {
#pragma unroll
      for (int t = 0; t < 4; t++) {
        bf16x8 kf = *(const bf16x8*)&Ks[(t * 16 + l16) * 128 + (((kbk << 2) + quad) ^ l16) * 8];
        sv[t] = __builtin_amdgcn_mfma_f32_16x16x32_bf16(qf[kbk], kf, sv[t], 0, 0, 0);
      }
    }
    if (kt == qt) {   // diagonal tile masking
#pragma unroll
      for (int t = 0; t < 4; t++) {
        const int key = kbase + t * 16 + l16;
#pragma unroll
        for (int r = 0; r < 4; r++)
          if (key > q0 + quad * 4 + r) sv[t][r] = -1e30f;
      }
    }
    float alpha[4];
#pragma unroll
    for (int r = 0; r < 4; r++) {
      float mx = fmaxf(fmaxf(sv[0][r], sv[1][r]), fmaxf(sv[2][r], sv[3][r]));
#pragma unroll
      for (int off = 8; off; off >>= 1) mx = fmaxf(mx, __shfl_xor(mx, off));
      const float mnew = fmaxf(mrow[r], mx);
      alpha[r] = __builtin_exp2f(mrow[r] - mnew);
      mrow[r] = mnew;
#pragma unroll
      for (int t = 0; t < 4; t++)
        sv[t][r] = __builtin_exp2f(sv[t][r] - mnew);
    }
#pragma unroll
    for (int dt = 0; dt < 8; dt++)
#pragma unroll
      for (int r = 0; r < 4; r++) oacc[dt][r] *= alpha[r];
#pragma unroll
    for (int r = 0; r < 4; r++) lacc[r] *= alpha[r];
    // P: C-layout -> A-layout via LDS round-trip (barriers: uniform trip count)
    __syncthreads();
#pragma unroll
    for (int r = 0; r < 4; r++)
#pragma unroll
      for (int t = 0; t < 4; t++)
        plds[wave][quad * 4 + r][t * 16 + l16] = f2bf(sv[t][r]);
    __syncthreads();
    bf16x8 pf0 = *(const bf16x8*)&plds[wave][l16][quad * 8];
    bf16x8 pf1 = *(const bf16x8*)&plds[wave][l16][32 + quad * 8];
    // row-sum of P via ones B-frag: lacc[r] += sum_k P[row][k] (replicated over l16)
    lacc = __builtin_amdgcn_mfma_f32_16x16x32_bf16(pf0, onesf, lacc, 0, 0, 0);
    lacc = __builtin_amdgcn_mfma_f32_16x16x32_bf16(pf1, onesf, lacc, 0, 0, 0);
#pragma unroll
    for (int dt = 0; dt < 8; dt++) {
      const int vrow = (dt * 16 + l16) * 64;
      bf16x8 vf0 = *(const bf16x8*)&Vs[vrow + ((quad) ^ (l16 & 7)) * 8];
      oacc[dt] = __builtin_amdgcn_mfma_f32_16x16x32_bf16(pf0, vf0, oacc[dt], 0, 0, 0);
      bf16x8 vf1 = *(const bf16x8*)&Vs[vrow + ((4 + quad) ^ (l16 & 7)) * 8];
      oacc[dt] = __builtin_amdgcn_mfma_f32_16x16x32_bf16(pf1, vf1, oacc[dt], 0, 0, 0);
    }
  }
#pragma unroll
  for (int dt = 0; dt < 8; dt++) {
#pragma unroll
    for (int r = 0; r < 4; r++) {
      const float v = oacc[dt][r] / lacc[r];
      ob[(size_t)(q0 + quad * 4 + r) * ATTN_N + h * HD + dt * 16 + l16] = f2bf(v);
    }
  }
}

extern "C" void kernel_launch(void* const* d_in, const int* in_sizes, int n_in,
                              void* d_out, int out_size, void* d_ws, size_t ws_size,
                              hipStream_t stream) {
  const void* hs_raw   = d_in[0];
  const void* cos_raw  = d_in[1];
  const void* sin_raw  = d_in[2];
  const void* wqkv_raw = d_in[3];
  const void* bqkv_raw = d_in[4];
  const void* wo_raw   = d_in[5];
  unsigned short* ws = (unsigned short*)d_ws;

  unsigned short* R1   = ws;                           // wt_qkv -> q/k/vt bufs -> wt_o
  unsigned short* R2   = R1 + (size_t)QKVN * HIDDEN;   // qkv -> attnb
  unsigned short* hs_c = R2 + (size_t)SEQ * QKVN;
  float* cosf  = (float*)(hs_c + (size_t)SEQ * HIDDEN);
  float* sinf  = cosf + SEQ * 64;
  float* biasf = sinf + SEQ * 64;
  int*   flag  = (int*)(biasf + QKVN);

  unsigned short* wt_qkv = R1;
  unsigned short* qbuf   = R1;
  unsigned short* kbuf   = qbuf + (size_t)NQH * SEQ * HD;
  unsigned short* vtbuf  = kbuf + (size_t)NKVH * SEQ * HD;
  unsigned short* wt_o   = R1;
  unsigned short* qkv    = R2;
  unsigned short* attnb  = R2;

  detect_dtype<<<1, 1, 0, stream>>>((const unsigned short*)hs_raw, flag);
  to_bf16_any<<<(SEQ * HIDDEN / 4 + 255) / 256, 256, 0, stream>>>(hs_raw, hs_c, SEQ * HIDDEN / 4, flag);
  to_f32_any<<<(SEQ * 64 / 4 + 255) / 256, 256, 0, stream>>>(cos_raw, cosf, SEQ * 64 / 4, flag);
  to_f32_any<<<(SEQ * 64 / 4 + 255) / 256, 256, 0, stream>>>(sin_raw, sinf, SEQ * 64 / 4, flag);
  to_f32_any<<<(QKVN / 4 + 255) / 256, 256, 0, stream>>>(bqkv_raw, biasf, QKVN / 4, flag);

  transpose_any<<<dim3(QKVN / 32, HIDDEN / 32), 256, 0, stream>>>(wqkv_raw, wt_qkv, HIDDEN, QKVN, flag);
  gemm_bt_8ph<<<dim3(QKVN / 256, SEQ / 256), 512, 0, stream>>>(hs_c, wt_qkv, biasf, qkv, SEQ, QKVN, HIDDEN, nullptr);
  rope_split<<<SEQ, 256, 0, stream>>>(qkv, cosf, sinf, qbuf, kbuf, vtbuf);
  attn_fwd<<<dim3(NQH, SEQ / 64), 256, 0, stream>>>(qbuf, kbuf, vtbuf, attnb);
  transpose_any<<<dim3(ATTN_N / 32, HIDDEN / 32), 256, 0, stream>>>(wo_raw, wt_o, HIDDEN, ATTN_N, flag);
  gemm_bt_8ph<<<dim3(ATTN_N / 256, SEQ / 256), 512, 0, stream>>>(attnb, wt_o, nullptr, d_out, SEQ, ATTN_N, HIDDEN, flag);
}